// Round 1
// baseline (126.851 us; speedup 1.0000x reference)
//
#include <hip/hip_runtime.h>

#define NUM_CP 64
#define D_MODEL 128

// Kernel 1: reduce control_points [64,128] -> B[128], C[128] in workspace.
// out[n][d] = B[d] + t[n] * C[d], with
//   B[d] = sum_{i=0}^{62} (1 - i) * cp[i][d]
//   C[d] = -cp[0][d] + sum_{i=1}^{62} cp[i][d]
__global__ void spline_coeffs(const float* __restrict__ cp, float* __restrict__ bc) {
    int d = threadIdx.x;  // 128 threads, one per model dim
    double B = 0.0, C = 0.0;
    for (int i = 0; i < NUM_CP - 1; ++i) {
        double v = (double)cp[i * D_MODEL + d];
        B += (1.0 - (double)i) * v;
        C += (i == 0) ? -v : v;
    }
    bc[d] = (float)B;
    bc[D_MODEL + d] = (float)C;
}

// Kernel 2: out[n][d] = B[d] + clip(t[n],0,1) * C[d], vectorized as float4.
__global__ __launch_bounds__(256) void spline_eval(const float* __restrict__ t,
                                                   const float* __restrict__ bc,
                                                   float* __restrict__ out, int n) {
    __shared__ float sbc[2 * D_MODEL];
    sbc[threadIdx.x] = bc[threadIdx.x];  // 256 threads load 256 floats
    __syncthreads();

    const long long total  = (long long)n * (D_MODEL / 4);  // float4 quads
    const long long stride = (long long)gridDim.x * blockDim.x;  // multiple of 32
    const long long g0     = (long long)blockIdx.x * blockDim.x + threadIdx.x;

    // Column within the row (in float4 units) is invariant across grid-stride
    // iterations because stride % 32 == 0 -> B/C fragments hoist out of loop.
    const int c = (int)(g0 & 31);
    const float4 b  = reinterpret_cast<const float4*>(sbc)[c];
    const float4 cc = reinterpret_cast<const float4*>(sbc)[32 + c];

    for (long long g = g0; g < total; g += stride) {
        const int row = (int)(g >> 5);
        float tv = t[row];
        tv = fminf(fmaxf(tv, 0.0f), 1.0f);
        float4 o;
        o.x = fmaf(tv, cc.x, b.x);
        o.y = fmaf(tv, cc.y, b.y);
        o.z = fmaf(tv, cc.z, b.z);
        o.w = fmaf(tv, cc.w, b.w);
        reinterpret_cast<float4*>(out)[g] = o;
    }
}

extern "C" void kernel_launch(void* const* d_in, const int* in_sizes, int n_in,
                              void* d_out, int out_size, void* d_ws, size_t ws_size,
                              hipStream_t stream) {
    const float* t  = (const float*)d_in[0];
    const float* cp = (const float*)d_in[1];
    float* out = (float*)d_out;
    float* bc  = (float*)d_ws;  // 256 floats = 1 KB scratch
    const int n = in_sizes[0];

    spline_coeffs<<<1, D_MODEL, 0, stream>>>(cp, bc);

    const long long total = (long long)n * (D_MODEL / 4);
    long long want = (total + 255) / 256;
    int blocks = (int)(want < 2048 ? want : 2048);
    spline_eval<<<blocks, 256, 0, stream>>>(t, bc, out, n);
}

// Round 3
// 105.705 us; speedup vs baseline: 1.2001x; 1.2001x over previous
//
#include <hip/hip_runtime.h>

#define NUM_CP 64
#define D_MODEL 128

typedef float f32x4 __attribute__((ext_vector_type(4)));

// out[n][d] = B[d] + clip(t[n],0,1) * C[d], with
//   B[d] = sum_{i=0}^{62} (1 - i) * cp[i][d]
//   C[d] = -cp[0][d] + sum_{i=1}^{62} cp[i][d]
// (exact algebraic collapse of the triangular-weight sum for t in [0,1])

__global__ void spline_coeffs(const float* __restrict__ cp, float* __restrict__ bc) {
    int d = threadIdx.x;  // 128 threads, one per model dim
    double B = 0.0, C = 0.0;
    for (int i = 0; i < NUM_CP - 1; ++i) {
        double v = (double)cp[i * D_MODEL + d];
        B += (1.0 - (double)i) * v;
        C += (i == 0) ? -v : v;
    }
    bc[d] = (float)B;
    bc[D_MODEL + d] = (float)C;
}

// Each wave owns 8 rows per iteration:
//   lanes 0-31  -> rows R0..R0+3   (lane = column c, one float4 quad per row)
//   lanes 32-63 -> rows R0+4..R0+7
// Per thread per iteration: 1 float4 load of t (broadcast within half-wave),
// 16 FMAs, 4 independent float4 NT stores. All int32 indexing.
__global__ __launch_bounds__(256) void spline_eval(const float* __restrict__ t,
                                                   const float* __restrict__ bc,
                                                   float* __restrict__ out, int n) {
    __shared__ float sbc[2 * D_MODEL];
    sbc[threadIdx.x] = bc[threadIdx.x];
    __syncthreads();

    const int lane = threadIdx.x & 63;
    const int c    = lane & 31;        // column in float4 units (0..31)
    const int half = lane >> 5;        // 0 or 1
    const int waveGlobal = blockIdx.x * 4 + (threadIdx.x >> 6);
    const int nWaves     = gridDim.x * 4;

    const f32x4 b  = reinterpret_cast<const f32x4*>(sbc)[c];
    const f32x4 cv = reinterpret_cast<const f32x4*>(sbc + D_MODEL)[c];
    f32x4* __restrict__ outq = reinterpret_cast<f32x4*>(out);

    const int rowStride = nWaves * 8;

    for (int R0 = waveGlobal * 8; R0 < n; R0 += rowStride) {
        const int R = R0 + half * 4;  // this thread's 4 rows: R..R+3
        if (R + 3 < n) {
            f32x4 t4 = *reinterpret_cast<const f32x4*>(t + R);
            float tv[4];
#pragma unroll
            for (int k = 0; k < 4; ++k) tv[k] = fminf(fmaxf(t4[k], 0.0f), 1.0f);
#pragma unroll
            for (int k = 0; k < 4; ++k) {
                f32x4 o;
                o.x = fmaf(tv[k], cv.x, b.x);
                o.y = fmaf(tv[k], cv.y, b.y);
                o.z = fmaf(tv[k], cv.z, b.z);
                o.w = fmaf(tv[k], cv.w, b.w);
                __builtin_nontemporal_store(o, &outq[(R + k) * 32 + c]);
            }
        } else {
            for (int k = 0; k < 4; ++k) {
                const int r = R + k;
                if (r < n) {
                    float tv = fminf(fmaxf(t[r], 0.0f), 1.0f);
                    f32x4 o;
                    o.x = fmaf(tv, cv.x, b.x);
                    o.y = fmaf(tv, cv.y, b.y);
                    o.z = fmaf(tv, cv.z, b.z);
                    o.w = fmaf(tv, cv.w, b.w);
                    __builtin_nontemporal_store(o, &outq[r * 32 + c]);
                }
            }
        }
    }
}

extern "C" void kernel_launch(void* const* d_in, const int* in_sizes, int n_in,
                              void* d_out, int out_size, void* d_ws, size_t ws_size,
                              hipStream_t stream) {
    const float* t  = (const float*)d_in[0];
    const float* cp = (const float*)d_in[1];
    float* out = (float*)d_out;
    float* bc  = (float*)d_ws;  // 256 floats = 1 KB scratch
    const int n = in_sizes[0];

    spline_coeffs<<<1, D_MODEL, 0, stream>>>(cp, bc);

    // 2048 blocks x 256 threads = 8 blocks/CU -> full 32-wave occupancy,
    // grid-stride keeps b/cv fragments in registers across iterations.
    const int waveTasks = (n + 7) / 8;              // 8 rows per wave-iter
    const int wantBlocks = (waveTasks + 3) / 4;     // 4 waves per block
    const int blocks = wantBlocks < 2048 ? wantBlocks : 2048;
    spline_eval<<<blocks, 256, 0, stream>>>(t, bc, out, n);
}